// Round 2
// baseline (870.581 us; speedup 1.0000x reference)
//
#include <hip/hip_runtime.h>
#include <cstdint>

// Problem constants (LocalizedFiltering: B=4, S=4096, D=2048, DH=1024)
#define BB 4
#define SS 4096           // power of 2: t = r & 4095, b = r >> 12
#define DD 2048
#define DH 1024
#define MM (BB * SS)      // 16384 rows
#define EPSV 1e-6f

typedef unsigned short u16;
typedef __bf16 bf16x8 __attribute__((ext_vector_type(8)));
typedef float f32x4 __attribute__((ext_vector_type(4)));

// ---------- helpers ----------

__device__ __forceinline__ u16 f2bf(float f) {           // RNE f32 -> bf16 bits
    uint32_t u = __float_as_uint(f);
    u += 0x7fffu + ((u >> 16) & 1u);
    return (u16)(u >> 16);
}

// async global->LDS, 16B per lane. LDS dest is wave-uniform base + lane*16.
__device__ __forceinline__ void async16(const void* g, void* l) {
    __builtin_amdgcn_global_load_lds(
        (const __attribute__((address_space(1))) uint32_t*)g,
        (__attribute__((address_space(3))) uint32_t*)l,
        16, 0, 0);
}

// ---------- elementwise converts / packs ----------

__global__ void cvt_f32_bf16(const float* __restrict__ in, u16* __restrict__ out, long n4) {
    long i = (long)blockIdx.x * blockDim.x + threadIdx.x;
    if (i >= n4) return;
    float4 v = *(const float4*)(in + i * 4);
    ushort4 o;
    o.x = f2bf(v.x); o.y = f2bf(v.y); o.z = f2bf(v.z); o.w = f2bf(v.w);
    *(ushort4*)(out + i * 4) = o;
}

// w [Nr, Dd, 2] f32 (tap-interleaved) -> out [Nr, 2*Dd] bf16 with tap0 cols [0,Dd), tap1 [Dd,2Dd)
__global__ void pack_w(const float* __restrict__ in, u16* __restrict__ out, int dshift) {
    int idx = blockIdx.x * 256 + threadIdx.x;   // pair index: e*Dd + d
    int Dd = 1 << dshift;
    int e = idx >> dshift;
    int d = idx & (Dd - 1);
    float2 v = *(const float2*)(in + (long)idx * 2);
    long rowbase = (long)e * (Dd * 2);
    out[rowbase + d] = f2bf(v.x);          // tap 0 (prev timestep)
    out[rowbase + Dd + d] = f2bf(v.y);     // tap 1 (current timestep)
}

// ---------- shifted 2-tap GEMM (bf16 MFMA) ----------
// LDS is staged in MFMA-fragment order: fragment read = base + lane*16B,
// conflict-free by construction. The per-lane *global* source pointers carry
// the permutation instead (global_load_lds writes wave-uniform-base + lane*16).
//
// LDS elem addr for (row 0..127, gchunk g 0..7 of the 64-col K-block):
//   ((row>>4)*2 + (g>>2))*512 + (g&3)*128 + (row&15)*8
// Staging chunk c (16 chunks of 1KB): lane l loads global
//   row = (c>>1)*16 + (l&15),  col elems = (c&1)*32 + (l>>4)*8
//
// C[r,n] = sum_{k<KD} Bt[n,k]*Aprev[r,k] + sum_{k<KD} Bt[n,KD+k]*Acur[r,k]
// Aprev row r = (r%S==0) ? cache[r/S] : A[r-1]
// MODE 1: out bf16 [M,NN] + bias; rows with t==S-1 also stored f32 to lf2out
// MODE 2: out f32  [M,NN] + bias + residual xres
template <int KD, int MODE>
__launch_bounds__(256, 2)
__global__ void gemm2tap(const u16* __restrict__ A,       // [M, KD] bf16
                         const u16* __restrict__ cache,   // [B, KD] bf16
                         const u16* __restrict__ Bt,      // [NN, 2*KD] bf16
                         const float* __restrict__ bias,  // [NN]
                         u16* __restrict__ obf,           // MODE 1
                         float* __restrict__ lf2out,      // MODE 1
                         const float* __restrict__ xres,  // MODE 2
                         float* __restrict__ yout)        // MODE 2
{
    constexpr int KTOT = 2 * KD;
    constexpr int NKB = KTOT / 64;     // K-blocks of 64
    constexpr int HALF = KD / 64;      // tap boundary in K-blocks
    constexpr int NN = (MODE == 1) ? DH : DD;

    const int tid = threadIdx.x;
    const int lane = tid & 63;
    const int wave = tid >> 6;
    const int bn = blockIdx.x;   // 128-col tile
    const int bm = blockIdx.y;   // 128-row tile

    __shared__ __align__(16) u16 As[128 * 64];
    __shared__ __align__(16) u16 Bs[128 * 64];

    // staging geometry (fragment-order): chunk = it*4 + wave
    const u16* aPrev[4];
    const u16* aCur[4];
    const u16* bPtr[4];
    u16* aLds[4];
    u16* bLds[4];
#pragma unroll
    for (int it = 0; it < 4; ++it) {
        int chunk = it * 4 + wave;                       // wave-uniform 0..15
        int rl = (chunk >> 1) * 16 + (lane & 15);        // row 0..127
        int ce = (chunk & 1) * 32 + (lane >> 4) * 8;     // col elem 0..56 within K-block
        long r = (long)bm * 128 + rl;
        aCur[it] = A + r * KD + ce;
        int tloc = ((int)r) & (SS - 1);
        aPrev[it] = (tloc == 0) ? (cache + (r >> 12) * KD + ce)
                                : (A + (r - 1) * KD + ce);
        long n = (long)bn * 128 + rl;
        bPtr[it] = Bt + n * KTOT + ce;
        aLds[it] = As + chunk * 512;                     // wave-uniform LDS base
        bLds[it] = Bs + chunk * 512;
    }

    f32x4 acc[4][4];
#pragma unroll
    for (int i = 0; i < 4; ++i)
#pragma unroll
        for (int j = 0; j < 4; ++j)
            acc[i][j] = (f32x4){0.f, 0.f, 0.f, 0.f};

    const int frow = lane & 15;
    const int fquad = lane >> 4;
    const int wm = (wave & 1) * 64;
    const int wn = (wave >> 1) * 64;
    const int aBase = (wm >> 4) * 1024 + lane * 8;       // fragment-order read base
    const int bBase = (wn >> 4) * 1024 + lane * 8;

    for (int kb = 0; kb < NKB; ++kb) {
        const int koff = kb * 64;
        __syncthreads();
#pragma unroll
        for (int it = 0; it < 4; ++it) {
            const u16* ag = (kb < HALF) ? (aPrev[it] + koff) : (aCur[it] + (koff - KD));
            async16(ag, aLds[it]);
            async16(bPtr[it] + koff, bLds[it]);
        }
        __syncthreads();
#pragma unroll
        for (int ks = 0; ks < 2; ++ks) {
            bf16x8 af[4], bfr[4];
#pragma unroll
            for (int i = 0; i < 4; ++i) {
                af[i]  = *(const bf16x8*)&As[aBase + i * 1024 + ks * 512];
                bfr[i] = *(const bf16x8*)&Bs[bBase + i * 1024 + ks * 512];
            }
#pragma unroll
            for (int i = 0; i < 4; ++i)
#pragma unroll
                for (int j = 0; j < 4; ++j)
                    acc[i][j] = __builtin_amdgcn_mfma_f32_16x16x32_bf16(af[i], bfr[j], acc[i][j], 0, 0, 0);
        }
    }

    // epilogue; C/D layout: col = lane&15, row = (lane>>4)*4 + v
    const long m0 = (long)bm * 128 + wm;
    const int n0 = bn * 128 + wn;
#pragma unroll
    for (int i = 0; i < 4; ++i) {
#pragma unroll
        for (int j = 0; j < 4; ++j) {
            int n = n0 + j * 16 + frow;
            float bv = bias[n];
#pragma unroll
            for (int v = 0; v < 4; ++v) {
                long m = m0 + i * 16 + fquad * 4 + v;
                float val = acc[i][j][v] + bv;
                if (MODE == 1) {
                    obf[m * NN + n] = f2bf(val);
                    if ((((int)m) & (SS - 1)) == (SS - 1))
                        lf2out[(m >> 12) * NN + n] = val;   // new lf2 cache (f32)
                } else {
                    val += xres[m * NN + n];                // residual in f32
                    yout[m * NN + n] = val;
                }
            }
        }
    }
}

// ---------- RMSNorm (in-place on d_out rows) ----------

__global__ void rmsnorm_inplace(float* __restrict__ y, const float* __restrict__ lnw) {
    const long r = blockIdx.x;
    float* row = y + r * DD;
    const int tid = threadIdx.x;

    float4 v0 = *(float4*)(row + tid * 4);
    float4 v1 = *(float4*)(row + 1024 + tid * 4);
    float s = v0.x * v0.x + v0.y * v0.y + v0.z * v0.z + v0.w * v0.w
            + v1.x * v1.x + v1.y * v1.y + v1.z * v1.z + v1.w * v1.w;
#pragma unroll
    for (int off = 32; off; off >>= 1) s += __shfl_xor(s, off, 64);

    __shared__ float red[4];
    if ((tid & 63) == 0) red[tid >> 6] = s;
    __syncthreads();
    float tot = red[0] + red[1] + red[2] + red[3];
    float inv = rsqrtf(tot * (1.0f / DD) + EPSV);

    float4 w0 = *(const float4*)(lnw + tid * 4);
    float4 w1 = *(const float4*)(lnw + 1024 + tid * 4);
    v0.x *= inv * w0.x; v0.y *= inv * w0.y; v0.z *= inv * w0.z; v0.w *= inv * w0.w;
    v1.x *= inv * w1.x; v1.y *= inv * w1.y; v1.z *= inv * w1.z; v1.w *= inv * w1.w;
    *(float4*)(row + tid * 4) = v0;
    *(float4*)(row + 1024 + tid * 4) = v1;
}

// lf1 = x[:, S-1, :]  (f32 copy, B*D = 8192 elems)
__global__ void lf1_copy(const float* __restrict__ x, float* __restrict__ out) {
    int idx = blockIdx.x * 256 + threadIdx.x;   // 0..8191
    int b = idx >> 11;
    int d = idx & (DD - 1);
    out[idx] = x[((long)b * SS + (SS - 1)) * DD + d];
}

// ---------- launch ----------

extern "C" void kernel_launch(void* const* d_in, const int* in_sizes, int n_in,
                              void* d_out, int out_size, void* d_ws, size_t ws_size,
                              hipStream_t stream) {
    const float* x    = (const float*)d_in[0];   // [M, D]
    const float* lf1c = (const float*)d_in[1];   // [B, D]
    const float* lf2c = (const float*)d_in[2];   // [B, DH]
    const float* w1   = (const float*)d_in[3];   // [DH, D, 2]
    const float* b1   = (const float*)d_in[4];   // [DH]
    const float* w2   = (const float*)d_in[5];   // [D, DH, 2]
    const float* b2   = (const float*)d_in[6];   // [D]
    const float* lnw  = (const float*)d_in[7];   // [D]

    float* out    = (float*)d_out;                        // lf_output [M, D]
    float* lf1out = out + (long)MM * DD;                  // [B, D]
    float* lf2out = lf1out + (long)BB * DD;               // [B, DH]

    char* ws = (char*)d_ws;
    u16* Xbf  = (u16*)ws; ws += (long)MM * DD * 2;        // 67.1 MB
    u16* o1bf = (u16*)ws; ws += (long)MM * DH * 2;        // 33.6 MB
    u16* W1b  = (u16*)ws; ws += (long)DH * (2 * DD) * 2;  // 8.4 MB
    u16* W2b  = (u16*)ws; ws += (long)DD * (2 * DH) * 2;  // 8.4 MB
    u16* c1   = (u16*)ws; ws += (long)BB * DD * 2;
    u16* c2   = (u16*)ws; ws += (long)BB * DH * 2;

    // 1) converts & weight packing
    cvt_f32_bf16<<<32768, 256, 0, stream>>>(x, Xbf, (long)MM * DD / 4);
    cvt_f32_bf16<<<8, 256, 0, stream>>>(lf1c, c1, (long)BB * DD / 4);
    cvt_f32_bf16<<<4, 256, 0, stream>>>(lf2c, c2, (long)BB * DH / 4);
    pack_w<<<(DH * DD) / 256, 256, 0, stream>>>(w1, W1b, 11);   // Dd = D = 2048
    pack_w<<<(DD * DH) / 256, 256, 0, stream>>>(w2, W2b, 10);   // Dd = DH = 1024

    // 2) conv1 GEMM: [M, 2D] x [2D, DH] -> o1 bf16 (+ lf2 rows f32)
    gemm2tap<DD, 1><<<dim3(DH / 128, MM / 128), 256, 0, stream>>>(
        Xbf, c1, W1b, b1, o1bf, lf2out, nullptr, nullptr);

    // 3) conv2 GEMM: [M, 2DH] x [2DH, D] -> y = o2 + x (f32, into d_out)
    gemm2tap<DH, 2><<<dim3(DD / 128, MM / 128), 256, 0, stream>>>(
        o1bf, c2, W2b, b2, nullptr, nullptr, x, out);

    // 4) RMSNorm in place + lf1 cache copy
    rmsnorm_inplace<<<MM, 256, 0, stream>>>(out, lnw);
    lf1_copy<<<BB * DD / 256, 256, 0, stream>>>(x, lf1out);
}

// Round 3
// 595.028 us; speedup vs baseline: 1.4631x; 1.4631x over previous
//
#include <hip/hip_runtime.h>
#include <cstdint>

// Problem constants (LocalizedFiltering: B=4, S=4096, D=2048, DH=1024)
#define BB 4
#define SS 4096           // power of 2: t = r & 4095, b = r >> 12
#define DD 2048
#define DH 1024
#define MM (BB * SS)      // 16384 rows
#define EPSV 1e-6f

typedef unsigned short u16;
typedef __bf16 bf16x8 __attribute__((ext_vector_type(8)));
typedef float f32x4 __attribute__((ext_vector_type(4)));

// ---------- helpers ----------

__device__ __forceinline__ u16 f2bf(float f) {           // RNE f32 -> bf16 bits
    uint32_t u = __float_as_uint(f);
    u += 0x7fffu + ((u >> 16) & 1u);
    return (u16)(u >> 16);
}

// async global->LDS, 16B per lane. LDS dest is wave-uniform base + lane*16.
__device__ __forceinline__ void async16(const void* g, void* l) {
    __builtin_amdgcn_global_load_lds(
        (const __attribute__((address_space(1))) uint32_t*)g,
        (__attribute__((address_space(3))) uint32_t*)l,
        16, 0, 0);
}

// ---------- elementwise converts / packs ----------

__global__ void cvt_f32_bf16(const float* __restrict__ in, u16* __restrict__ out, long n4) {
    long i = (long)blockIdx.x * blockDim.x + threadIdx.x;
    if (i >= n4) return;
    float4 v = *(const float4*)(in + i * 4);
    ushort4 o;
    o.x = f2bf(v.x); o.y = f2bf(v.y); o.z = f2bf(v.z); o.w = f2bf(v.w);
    *(ushort4*)(out + i * 4) = o;
}

// w [Nr, Dd, 2] f32 (tap-interleaved) -> out [Nr, 2*Dd] bf16 with tap0 cols [0,Dd), tap1 [Dd,2Dd)
__global__ void pack_w(const float* __restrict__ in, u16* __restrict__ out, int dshift) {
    int idx = blockIdx.x * 256 + threadIdx.x;   // pair index: e*Dd + d
    int Dd = 1 << dshift;
    int e = idx >> dshift;
    int d = idx & (Dd - 1);
    float2 v = *(const float2*)(in + (long)idx * 2);
    long rowbase = (long)e * (Dd * 2);
    out[rowbase + d] = f2bf(v.x);          // tap 0 (prev timestep)
    out[rowbase + Dd + d] = f2bf(v.y);     // tap 1 (current timestep)
}

// ---------- shifted 2-tap GEMM (bf16 MFMA, XOR-swizzled LDS) ----------
// Staging (coalesced, round-1 geometry): chunk = it*4+wave covers 8 rows x 64 elems.
//   lane l: row = chunk*8 + (l>>3); global 16B-chunk c_g = (l&7) ^ (l>>3)
//   (XOR permutes lanes WITHIN the same 128B segment -> coalescing preserved).
//   LDS slot (implicit, base + l*16): row-in-chunk l>>3, chunk-slot l&7
//   => row r's global chunk c is stored at slot c ^ (r&7).
// Fragment read: lane reads row (wm+i*16+frow), global chunk ks*4+fquad
//   => LDS chunk slot (ks*4+fquad) ^ (frow&7). For each (i,ks) the 64 lanes
//   spread 8-per-bank-group over all 8 groups: balanced, conflict-free b128.
//
// C[r,n] = sum_{k<KD} Bt[n,k]*Aprev[r,k] + sum_{k<KD} Bt[n,KD+k]*Acur[r,k]
// Aprev row r = (r%S==0) ? cache[r/S] : A[r-1]
// MODE 1: out bf16 [M,NN] + bias; rows with t==S-1 also stored f32 to lf2out
// MODE 2: out f32  [M,NN] + bias + residual xres
template <int KD, int MODE>
__launch_bounds__(256, 2)
__global__ void gemm2tap(const u16* __restrict__ A,       // [M, KD] bf16
                         const u16* __restrict__ cache,   // [B, KD] bf16
                         const u16* __restrict__ Bt,      // [NN, 2*KD] bf16
                         const float* __restrict__ bias,  // [NN]
                         u16* __restrict__ obf,           // MODE 1
                         float* __restrict__ lf2out,      // MODE 1
                         const float* __restrict__ xres,  // MODE 2
                         float* __restrict__ yout)        // MODE 2
{
    constexpr int KTOT = 2 * KD;
    constexpr int NKB = KTOT / 64;     // K-blocks of 64
    constexpr int HALF = KD / 64;      // tap boundary in K-blocks
    constexpr int NN = (MODE == 1) ? DH : DD;

    const int tid = threadIdx.x;
    const int lane = tid & 63;
    const int wave = tid >> 6;
    const int bm = blockIdx.x;   // 128-row tile (fastest -> same-A blocks share XCD)
    const int bn = blockIdx.y;   // 128-col tile

    __shared__ __align__(16) u16 As[128 * 64];
    __shared__ __align__(16) u16 Bs[128 * 64];

    // staging geometry: chunk = it*4 + wave; 8 rows x 128B, XOR-permuted lanes
    const int lrow = lane >> 3;                      // 0..7 row within chunk
    const int lcol = ((lane & 7) ^ lrow) * 8;        // global col elem (XOR swizzle)

    const u16* aPrev[4];
    const u16* aCur[4];
    const u16* bPtr[4];
    u16* aLds[4];
    u16* bLds[4];
#pragma unroll
    for (int it = 0; it < 4; ++it) {
        int chunk = it * 4 + wave;                 // wave-uniform 0..15
        int rl = chunk * 8 + lrow;                 // 0..127
        long r = (long)bm * 128 + rl;
        aCur[it] = A + r * KD + lcol;
        int tloc = ((int)r) & (SS - 1);
        aPrev[it] = (tloc == 0) ? (cache + (r >> 12) * KD + lcol)
                                : (A + (r - 1) * KD + lcol);
        long n = (long)bn * 128 + rl;
        bPtr[it] = Bt + n * KTOT + lcol;
        aLds[it] = As + chunk * 512;               // wave-uniform LDS base
        bLds[it] = Bs + chunk * 512;
    }

    f32x4 acc[4][4];
#pragma unroll
    for (int i = 0; i < 4; ++i)
#pragma unroll
        for (int j = 0; j < 4; ++j)
            acc[i][j] = (f32x4){0.f, 0.f, 0.f, 0.f};

    const int frow = lane & 15;
    const int fquad = lane >> 4;
    const int wm = (wave & 1) * 64;
    const int wn = (wave >> 1) * 64;
    const int fxor = frow & 7;

    for (int kb = 0; kb < NKB; ++kb) {
        const int koff = kb * 64;
        __syncthreads();
#pragma unroll
        for (int it = 0; it < 4; ++it) {
            const u16* ag = (kb < HALF) ? (aPrev[it] + koff) : (aCur[it] + (koff - KD));
            async16(ag, aLds[it]);
            async16(bPtr[it] + koff, bLds[it]);
        }
        __syncthreads();
#pragma unroll
        for (int ks = 0; ks < 2; ++ks) {
            const int cs = ((ks * 4 + fquad) ^ fxor) * 8;   // swizzled chunk offset (elems)
            bf16x8 af[4], bfr[4];
#pragma unroll
            for (int i = 0; i < 4; ++i) {
                af[i]  = *(const bf16x8*)&As[(wm + i * 16 + frow) * 64 + cs];
                bfr[i] = *(const bf16x8*)&Bs[(wn + i * 16 + frow) * 64 + cs];
            }
#pragma unroll
            for (int i = 0; i < 4; ++i)
#pragma unroll
                for (int j = 0; j < 4; ++j)
                    acc[i][j] = __builtin_amdgcn_mfma_f32_16x16x32_bf16(af[i], bfr[j], acc[i][j], 0, 0, 0);
        }
    }

    // epilogue; C/D layout: col = lane&15, row = (lane>>4)*4 + v
    const long m0 = (long)bm * 128 + wm;
    const int n0 = bn * 128 + wn;
#pragma unroll
    for (int i = 0; i < 4; ++i) {
#pragma unroll
        for (int j = 0; j < 4; ++j) {
            int n = n0 + j * 16 + frow;
            float bv = bias[n];
#pragma unroll
            for (int v = 0; v < 4; ++v) {
                long m = m0 + i * 16 + fquad * 4 + v;
                float val = acc[i][j][v] + bv;
                if (MODE == 1) {
                    obf[m * NN + n] = f2bf(val);
                    if ((((int)m) & (SS - 1)) == (SS - 1))
                        lf2out[(m >> 12) * NN + n] = val;   // new lf2 cache (f32)
                } else {
                    val += xres[m * NN + n];                // residual in f32
                    yout[m * NN + n] = val;
                }
            }
        }
    }
}

// ---------- RMSNorm (in-place on d_out rows) ----------

__global__ void rmsnorm_inplace(float* __restrict__ y, const float* __restrict__ lnw) {
    const long r = blockIdx.x;
    float* row = y + r * DD;
    const int tid = threadIdx.x;

    float4 v0 = *(float4*)(row + tid * 4);
    float4 v1 = *(float4*)(row + 1024 + tid * 4);
    float s = v0.x * v0.x + v0.y * v0.y + v0.z * v0.z + v0.w * v0.w
            + v1.x * v1.x + v1.y * v1.y + v1.z * v1.z + v1.w * v1.w;
#pragma unroll
    for (int off = 32; off; off >>= 1) s += __shfl_xor(s, off, 64);

    __shared__ float red[4];
    if ((tid & 63) == 0) red[tid >> 6] = s;
    __syncthreads();
    float tot = red[0] + red[1] + red[2] + red[3];
    float inv = rsqrtf(tot * (1.0f / DD) + EPSV);

    float4 w0 = *(const float4*)(lnw + tid * 4);
    float4 w1 = *(const float4*)(lnw + 1024 + tid * 4);
    v0.x *= inv * w0.x; v0.y *= inv * w0.y; v0.z *= inv * w0.z; v0.w *= inv * w0.w;
    v1.x *= inv * w1.x; v1.y *= inv * w1.y; v1.z *= inv * w1.z; v1.w *= inv * w1.w;
    *(float4*)(row + tid * 4) = v0;
    *(float4*)(row + 1024 + tid * 4) = v1;
}

// lf1 = x[:, S-1, :]  (f32 copy, B*D = 8192 elems)
__global__ void lf1_copy(const float* __restrict__ x, float* __restrict__ out) {
    int idx = blockIdx.x * 256 + threadIdx.x;   // 0..8191
    int b = idx >> 11;
    int d = idx & (DD - 1);
    out[idx] = x[((long)b * SS + (SS - 1)) * DD + d];
}

// ---------- launch ----------

extern "C" void kernel_launch(void* const* d_in, const int* in_sizes, int n_in,
                              void* d_out, int out_size, void* d_ws, size_t ws_size,
                              hipStream_t stream) {
    const float* x    = (const float*)d_in[0];   // [M, D]
    const float* lf1c = (const float*)d_in[1];   // [B, D]
    const float* lf2c = (const float*)d_in[2];   // [B, DH]
    const float* w1   = (const float*)d_in[3];   // [DH, D, 2]
    const float* b1   = (const float*)d_in[4];   // [DH]
    const float* w2   = (const float*)d_in[5];   // [D, DH, 2]
    const float* b2   = (const float*)d_in[6];   // [D]
    const float* lnw  = (const float*)d_in[7];   // [D]

    float* out    = (float*)d_out;                        // lf_output [M, D]
    float* lf1out = out + (long)MM * DD;                  // [B, D]
    float* lf2out = lf1out + (long)BB * DD;               // [B, DH]

    char* ws = (char*)d_ws;
    u16* Xbf  = (u16*)ws; ws += (long)MM * DD * 2;        // 67.1 MB
    u16* o1bf = (u16*)ws; ws += (long)MM * DH * 2;        // 33.6 MB
    u16* W1b  = (u16*)ws; ws += (long)DH * (2 * DD) * 2;  // 8.4 MB
    u16* W2b  = (u16*)ws; ws += (long)DD * (2 * DH) * 2;  // 8.4 MB
    u16* c1   = (u16*)ws; ws += (long)BB * DD * 2;
    u16* c2   = (u16*)ws; ws += (long)BB * DH * 2;

    // 1) converts & weight packing
    cvt_f32_bf16<<<32768, 256, 0, stream>>>(x, Xbf, (long)MM * DD / 4);
    cvt_f32_bf16<<<8, 256, 0, stream>>>(lf1c, c1, (long)BB * DD / 4);
    cvt_f32_bf16<<<4, 256, 0, stream>>>(lf2c, c2, (long)BB * DH / 4);
    pack_w<<<(DH * DD) / 256, 256, 0, stream>>>(w1, W1b, 11);   // Dd = D = 2048
    pack_w<<<(DD * DH) / 256, 256, 0, stream>>>(w2, W2b, 10);   // Dd = DH = 1024

    // 2) conv1 GEMM: [M, 2D] x [2D, DH] -> o1 bf16 (+ lf2 rows f32)
    gemm2tap<DD, 1><<<dim3(MM / 128, DH / 128), 256, 0, stream>>>(
        Xbf, c1, W1b, b1, o1bf, lf2out, nullptr, nullptr);

    // 3) conv2 GEMM: [M, 2DH] x [2DH, D] -> y = o2 + x (f32, into d_out)
    gemm2tap<DH, 2><<<dim3(MM / 128, DD / 128), 256, 0, stream>>>(
        o1bf, c2, W2b, b2, nullptr, nullptr, x, out);

    // 4) RMSNorm in place + lf1 cache copy
    rmsnorm_inplace<<<MM, 256, 0, stream>>>(out, lnw);
    lf1_copy<<<BB * DD / 256, 256, 0, stream>>>(x, lf1out);
}